// Round 11
// baseline (236.183 us; speedup 1.0000x reference)
//
#include <hip/hip_runtime.h>
#include <math.h>

// Problem constants (fixed by the reference's shapes)
#define NROWS   131072      // 32*64*64 spatial positions
#define DFEAT   64          // feature dim (C)
#define KHALF   512         // rows per embedding table
#define HW      4096        // 64*64
#define CHW     262144      // 64*4096
#define NQOUT   8388608     // 32*64*64*64 quantized elements
#define NBLK    2048        // vq_main grid: 64 rows/block -> 8 blocks/CU

typedef __attribute__((ext_vector_type(8))) short   bf16x8;
typedef __attribute__((ext_vector_type(4))) float   f32x4;

__device__ __forceinline__ unsigned short f2bf(float f) {
    unsigned int u = __float_as_uint(f);
    u += 0x7FFFu + ((u >> 16) & 1u);          // round-to-nearest-even
    return (unsigned short)(u >> 16);
}
__device__ __forceinline__ float bf2f(unsigned short h) {
    return __uint_as_float(((unsigned int)h) << 16);
}

// ---------------------------------------------------------------------------
// Kernel 0 (fused prep): zero ws accumulators + cnh + pack fragments.
//   - tau < 1536: zero {loss, hist} region
//   - tau < 1024: cnh[k] = 0.5*||codes[k]||^2 (fp32 exact)
//   - all 16384:  pack codes into MFMA-B-fragment order, hi/lo bf16 split
// Layout: fragbuf[tile(64)][frag(4)][lane(64)][j(8)] ushort
//   frag 0: hi, k=0..31    frag 1: hi, k=32..63
//   frag 2: lo, k=0..31    frag 3: lo, k=32..63
// lane L of frag f holds code (tile*16 + (L&15)), feats kb..kb+7,
//   kb = (f&1)*32 + (L>>4)*8    -> ready for mfma_f32_16x16x32_bf16 B operand
// Session ledger (hard-won):
//  - NO device-scope fences (r1/r2: per-wave agent fence = thousands of L2
//    writebacks, ~80us). Cross-kernel visibility via dispatch boundary.
//  - All waves/blocks stream fragbuf in the SAME tile order (r5: disjoint
//    halves thrashed L3 -> FETCH 18.5MB -> 604MB, HBM-bound; natural skew
//    of a shared sequence is fine, r6/r8).
//  - Streaming traffic must be per-BLOCK, not per-wave (r8 regressed;
//    r9/r10: LDS staging fixed it).
//  - Occupancy lever confirmed to 8 blk/CU + staging (r10: 83.6us,
//    MfmaUtil 36). This round halves barrier/loop overhead: 2 tiles per
//    ping-pong buffer -> 32 barriers instead of 64.
// ---------------------------------------------------------------------------
__global__ void vq_prep(const float* __restrict__ e0, const float* __restrict__ e1,
                        const float* __restrict__ e2, const int* __restrict__ idxp,
                        float* __restrict__ wsf, float* __restrict__ cnh,
                        unsigned short* __restrict__ fragbuf) {
    int tau = blockIdx.x * 256 + threadIdx.x;   // 64 blocks * 256 = 16384
    if (tau < 1536) wsf[tau] = 0.f;             // loss @0, hist @256..

    int idx = idxp[0];
    const float* sel = (idx == 2) ? e2 : e1;

    if (tau < 1024) {
        const float* row = (tau < KHALF) ? (e0 + (size_t)tau * DFEAT)
                                         : (sel + (size_t)(tau - KHALF) * DFEAT);
        float s = 0.f;
#pragma unroll
        for (int c = 0; c < DFEAT; ++c) s = fmaf(row[c], row[c], s);
        cnh[tau] = 0.5f * s;
    }

    int tile = tau >> 8;
    int rem  = tau & 255;
    int f    = rem >> 6;
    int L    = rem & 63;
    int code = tile * 16 + (L & 15);
    int kb   = (f & 1) * 32 + (L >> 4) * 8;
    int lo_f = f >> 1;
    const float* src = (code < KHALF) ? (e0 + (size_t)code * DFEAT)
                                      : (sel + (size_t)(code - KHALF) * DFEAT);
    unsigned short* dst = fragbuf + (size_t)tau * 8;
#pragma unroll
    for (int j = 0; j < 8; ++j) {
        float v = src[kb + j];
        unsigned short hb = f2bf(v);
        dst[j] = lo_f ? f2bf(v - bf2f(hb)) : hb;
    }
}

// ---------------------------------------------------------------------------
// Kernel 1: main VQ. Block = 256 threads = 4 waves; 64 rows/block
// (ONE 16-row MFMA tile per wave) -> grid 2048 -> 8 blocks/CU ->
// ~8 waves/SIMD (r10 geometry). B-fragments staged into LDS per BLOCK,
// TWO tiles per ping-pong buffer -> one barrier per 2 tiles (32 total).
// Each wave keeps 2 fragments in flight (tiles t+2,t+3 while computing
// t,t+1). Inner math bitwise-identical to r10: ONE 8-deep MFMA chain per
// tile, acc seeded with -0.5||c||^2. Ascending-k order everywhere.
// ---------------------------------------------------------------------------
#define MFMA_TILE(BUF, TI, TT)                                                 \
    {                                                                          \
        bf16x8 b0 = ldsf[BUF][TI][0][L];                                       \
        bf16x8 b1 = ldsf[BUF][TI][1][L];                                       \
        bf16x8 b2 = ldsf[BUF][TI][2][L];                                       \
        bf16x8 b3 = ldsf[BUF][TI][3][L];                                       \
        const float cn_ = -cnh[(TT) * 16 + m];                                 \
        const int kt_ = (TT) * 16 + m;                                         \
        f32x4 acc = {cn_, cn_, cn_, cn_};                                      \
        acc = __builtin_amdgcn_mfma_f32_16x16x32_bf16(ahi0, b0, acc, 0, 0, 0); \
        acc = __builtin_amdgcn_mfma_f32_16x16x32_bf16(ahi1, b1, acc, 0, 0, 0); \
        acc = __builtin_amdgcn_mfma_f32_16x16x32_bf16(ahi0, b2, acc, 0, 0, 0); \
        acc = __builtin_amdgcn_mfma_f32_16x16x32_bf16(ahi1, b3, acc, 0, 0, 0); \
        acc = __builtin_amdgcn_mfma_f32_16x16x32_bf16(alo0, b0, acc, 0, 0, 0); \
        acc = __builtin_amdgcn_mfma_f32_16x16x32_bf16(alo1, b1, acc, 0, 0, 0); \
        acc = __builtin_amdgcn_mfma_f32_16x16x32_bf16(alo0, b2, acc, 0, 0, 0); \
        acc = __builtin_amdgcn_mfma_f32_16x16x32_bf16(alo1, b3, acc, 0, 0, 0); \
        _Pragma("unroll")                                                      \
        for (int r = 0; r < 4; ++r) {                                          \
            if (acc[r] > best[r]) { best[r] = acc[r]; bidx[r] = kt_; }         \
        }                                                                      \
    }

__global__ __launch_bounds__(256, 8) void vq_main(
        const float* __restrict__ x,
        const float* __restrict__ e0, const float* __restrict__ e1,
        const float* __restrict__ e2, const int* __restrict__ idxp,
        const float* __restrict__ cnh, const unsigned short* __restrict__ fragbuf,
        float* __restrict__ out, float* __restrict__ loss_acc,
        int* __restrict__ hist) {
    __shared__ float  xsq_s[64];
    __shared__ float  sc_s[64];
    __shared__ int    bk_s[64];
    __shared__ bf16x8 ldsf[2][2][4][64];   // [pingpong][tile][frag][lane], 16 KB

    const int t = threadIdx.x;
    const int w = t >> 6;          // wave in block (owns rows [w*16, w*16+16))
    const int L = t & 63;          // lane
    const int q = L >> 4;          // quad
    const int m = L & 15;

    const int rowbase = blockIdx.x * 64;   // 2048 blocks; never straddles an image
    const int n  = rowbase >> 12;
    const int s0 = rowbase & 4095;

    const int idx = idxp[0];
    const float* sel = (idx == 2) ? e2 : e1;
    const int ntiles = (idx == 0) ? 32 : 64;   // always divisible by 4

    // ---- A fragments: one 16-row tile per wave, hi/lo bf16 + ||x||^2 ----
    bf16x8 ahi0, ahi1, alo0, alo1;
    {
        const float* xr = x + (size_t)n * CHW + (s0 + w * 16) + m;
        float xs = 0.f;
#pragma unroll
        for (int h = 0; h < 2; ++h) {
            bf16x8 hi, lo;
#pragma unroll
            for (int j = 0; j < 8; ++j) {
                int c = h * 32 + q * 8 + j;
                float v = xr[(size_t)c * HW];
                xs = fmaf(v, v, xs);
                unsigned short hb = f2bf(v);
                unsigned short lb = f2bf(v - bf2f(hb));
                hi[j] = (short)hb;
                lo[j] = (short)lb;
            }
            if (h == 0) { ahi0 = hi; alo0 = lo; } else { ahi1 = hi; alo1 = lo; }
        }
        // full ||x_row||^2: row features live in lanes {m, m+16, m+32, m+48}
        xs += __shfl_xor(xs, 16, 64);
        xs += __shfl_xor(xs, 32, 64);
        if (q == 0) xsq_s[w * 16 + m] = xs;
    }

    // ---- stream code tiles via LDS; score = x.c - 0.5||c||^2, argMAX ----
    const bf16x8* fb = (const bf16x8*)fragbuf;
    float best[4];
    int   bidx[4];
#pragma unroll
    for (int i = 0; i < 4; ++i) { best[i] = -3.4e38f; bidx[i] = 0; }

    // prologue: stage tiles 0,1 into buf0; tiles 2,3 in flight
    bf16x8 P0 = fb[(0 * 4 + w) * 64 + L];
    bf16x8 P1 = fb[(1 * 4 + w) * 64 + L];
    ldsf[0][0][w][L] = P0;
    ldsf[0][1][w][L] = P1;
    P0 = fb[(2 * 4 + w) * 64 + L];
    P1 = fb[(3 * 4 + w) * 64 + L];
    __syncthreads();                                 // buf0 ready
    bf16x8 Q0, Q1;

    for (int tt = 0; tt < ntiles; tt += 4) {
        // ---- STEP A: compute tiles tt,tt+1 from buf0; stage tt+2,tt+3 ----
        {
            const int ta = (tt + 4 < ntiles) ? tt + 4 : ntiles - 1;
            const int tb = (tt + 5 < ntiles) ? tt + 5 : ntiles - 1;
            Q0 = fb[(ta * 4 + w) * 64 + L];          // prefetch tiles tt+4,tt+5
            Q1 = fb[(tb * 4 + w) * 64 + L];
            MFMA_TILE(0, 0, tt);
            MFMA_TILE(0, 1, tt + 1);
            ldsf[1][0][w][L] = P0;                   // tiles tt+2,tt+3 -> buf1
            ldsf[1][1][w][L] = P1;
            __syncthreads();
        }
        // ---- STEP B: compute tiles tt+2,tt+3 from buf1; stage tt+4,tt+5 ----
        {
            const int ta = (tt + 6 < ntiles) ? tt + 6 : ntiles - 1;
            const int tb = (tt + 7 < ntiles) ? tt + 7 : ntiles - 1;
            P0 = fb[(ta * 4 + w) * 64 + L];          // prefetch tiles tt+6,tt+7
            P1 = fb[(tb * 4 + w) * 64 + L];
            MFMA_TILE(1, 0, tt + 2);
            MFMA_TILE(1, 1, tt + 3);
            ldsf[0][0][w][L] = Q0;                   // tiles tt+4,tt+5 -> buf0
            ldsf[0][1][w][L] = Q1;
            __syncthreads();
        }
    }

    // ---- reduce argmax across the 16 cols (lane bits 0-3) ----
#pragma unroll
    for (int i = 0; i < 4; ++i) {
        float b = best[i]; int k = bidx[i];
#pragma unroll
        for (int off = 1; off < 16; off <<= 1) {
            float ob = __shfl_xor(b, off, 64);
            int   ok = __shfl_xor(k, off, 64);
            if (ob > b || (ob == b && ok < k)) { b = ob; k = ok; }
        }
        if (m == 0) {   // D row = q*4 + i
            int row = w * 16 + q * 4 + i;
            sc_s[row] = b; bk_s[row] = k;
        }
    }
    __syncthreads();

    // ---- epilogue part 1: loss + histogram, one thread per row (t < 64) ----
    if (t < 64) {
        const int k = bk_s[t];
        float dist = xsq_s[t] - 2.f * sc_s[t];   // ||x||^2 - 2x.c + ||c||^2
        float l = dist;
#pragma unroll
        for (int off = 32; off > 0; off >>= 1) l += __shfl_down(l, off, 64);
        if (L == 0) atomicAdd(loss_acc, l);
        atomicAdd(&hist[k], 1);
    }

    // ---- epilogue part 2: gather-copy, 4 threads per row (16 feats each) ----
    {
        const int row  = t & 63;
        const int quad = t >> 6;
        const int k = bk_s[row];
        const float* cp = ((k < KHALF) ? (e0 + (size_t)k * DFEAT)
                                       : (sel + (size_t)(k - KHALF) * DFEAT)) + quad * 16;
        const float4* cp4 = (const float4*)cp;
        float* op = out + (size_t)n * CHW + (s0 + row);
#pragma unroll
        for (int c4 = 0; c4 < 4; ++c4) {
            float4 v = cp4[c4];
            int c = quad * 16 + 4 * c4;
            op[(size_t)(c + 0) * HW] = v.x;
            op[(size_t)(c + 1) * HW] = v.y;
            op[(size_t)(c + 2) * HW] = v.z;
            op[(size_t)(c + 3) * HW] = v.w;
        }
    }
}

// ---------------------------------------------------------------------------
// Kernel 2: finalize — loss scalar + perplexity from histogram. One block.
// Cross-kernel visibility of hist/loss comes from the dispatch boundary.
// ---------------------------------------------------------------------------
__global__ void vq_finalize(const float* __restrict__ wsf, const int* __restrict__ hist,
                            float* __restrict__ out) {
    __shared__ double partial[16];
    const int t = threadIdx.x;          // 1024 threads, one per bin
    double p = (double)hist[t] / (double)NROWS;
    double term = p * log(p + 1e-10);   // p==0 -> exactly 0
#pragma unroll
    for (int off = 32; off > 0; off >>= 1) term += __shfl_down(term, off, 64);
    if ((t & 63) == 0) partial[t >> 6] = term;
    __syncthreads();
    if (t == 0) {
        double s = 0.0;
        for (int i = 0; i < 16; ++i) s += partial[i];
        out[NQOUT + 1] = (float)exp(-s);                       // perplexity
        out[NQOUT]     = 1.25f * (wsf[0] / (float)NQOUT);      // q_loss + 0.25*e_loss
    }
}

// ---------------------------------------------------------------------------
extern "C" void kernel_launch(void* const* d_in, const int* in_sizes, int n_in,
                              void* d_out, int out_size, void* d_ws, size_t ws_size,
                              hipStream_t stream) {
    const float* x  = (const float*)d_in[0];
    const float* e0 = (const float*)d_in[1];
    const float* e1 = (const float*)d_in[2];
    const float* e2 = (const float*)d_in[3];
    const int* idxp = (const int*)d_in[4];
    float* out = (float*)d_out;

    // ws layout (floats): [0] loss | [256..1280) hist
    //                     [2048..3072) cnh | [4096..) fragbuf: 131072 ushort
    float* wsf      = (float*)d_ws;
    float* loss_acc = wsf;
    int*   hist     = (int*)(wsf + 256);
    float* cnh      = wsf + 2048;
    unsigned short* fragbuf = (unsigned short*)(wsf + 4096);

    vq_prep<<<64, 256, 0, stream>>>(e0, e1, e2, idxp, wsf, cnh, fragbuf);
    vq_main<<<NBLK, 256, 0, stream>>>(x, e0, e1, e2, idxp, cnh, fragbuf,
                                      out, loss_acc, hist);
    vq_finalize<<<1, 1024, 0, stream>>>(wsf, hist, out);
}

// Round 12
// 161.754 us; speedup vs baseline: 1.4601x; 1.4601x over previous
//
#include <hip/hip_runtime.h>
#include <math.h>

// Problem constants (fixed by the reference's shapes)
#define NROWS   131072      // 32*64*64 spatial positions
#define DFEAT   64          // feature dim (C)
#define KHALF   512         // rows per embedding table
#define HW      4096        // 64*64
#define CHW     262144      // 64*4096
#define NQOUT   8388608     // 32*64*64*64 quantized elements
#define NBLK    2048        // vq_main grid: 64 rows/block

typedef __attribute__((ext_vector_type(8))) short   bf16x8;
typedef __attribute__((ext_vector_type(4))) float   f32x4;

__device__ __forceinline__ unsigned short f2bf(float f) {
    unsigned int u = __float_as_uint(f);
    u += 0x7FFFu + ((u >> 16) & 1u);          // round-to-nearest-even
    return (unsigned short)(u >> 16);
}
__device__ __forceinline__ float bf2f(unsigned short h) {
    return __uint_as_float(((unsigned int)h) << 16);
}

// ---------------------------------------------------------------------------
// Kernel 0 (fused prep): zero ws accumulators + cnh + pack fragments.
//   - tau < 1536: zero {loss, hist} region
//   - tau < 1024: cnh[k] = 0.5*||codes[k]||^2 (fp32 exact)
//   - all 16384:  pack codes into MFMA-B-fragment order, hi/lo bf16 split
// Layout: fragbuf[tile(64)][frag(4)][lane(64)][j(8)] ushort
//   frag 0: hi, k=0..31    frag 1: hi, k=32..63
//   frag 2: lo, k=0..31    frag 3: lo, k=32..63
// lane L of frag f holds code (tile*16 + (L&15)), feats kb..kb+7,
//   kb = (f&1)*32 + (L>>4)*8    -> ready for mfma_f32_16x16x32_bf16 B operand
// Session ledger (hard-won):
//  - NO device-scope fences (r1/r2: per-wave agent fence = thousands of L2
//    writebacks, ~80us). Cross-kernel visibility via dispatch boundary.
//  - All waves/blocks stream fragbuf in the SAME tile order (r5: disjoint
//    halves thrashed L3 -> FETCH 604MB, HBM-bound; skew of a shared
//    sequence is fine, r6/r8).
//  - Streaming traffic must be per-BLOCK, not per-wave (r8 regressed;
//    r9/r10: LDS staging fixed it).
//  - Arch-VGPR pool is ~256/SIMD: launch_bounds waves-arg w caps VGPRs at
//    ~256/w (observed: 2->128, 4->64, 6->42, 8->32). r10 (arg 8, cap 32)
//    spilled mildly (+18MB scratch traffic); r11's 2-tile variant (+16
//    live regs at the same cap) spilled catastrophically (WRITE 388MB,
//    2x slower). NEVER exceed the cap with live loop state.
//  - This round: r10 structure exactly, arg 8->6 (cap ~42) to absorb the
//    spill; 6 blocks/CU instead of 8.
// ---------------------------------------------------------------------------
__global__ void vq_prep(const float* __restrict__ e0, const float* __restrict__ e1,
                        const float* __restrict__ e2, const int* __restrict__ idxp,
                        float* __restrict__ wsf, float* __restrict__ cnh,
                        unsigned short* __restrict__ fragbuf) {
    int tau = blockIdx.x * 256 + threadIdx.x;   // 64 blocks * 256 = 16384
    if (tau < 1536) wsf[tau] = 0.f;             // loss @0, hist @256..

    int idx = idxp[0];
    const float* sel = (idx == 2) ? e2 : e1;

    if (tau < 1024) {
        const float* row = (tau < KHALF) ? (e0 + (size_t)tau * DFEAT)
                                         : (sel + (size_t)(tau - KHALF) * DFEAT);
        float s = 0.f;
#pragma unroll
        for (int c = 0; c < DFEAT; ++c) s = fmaf(row[c], row[c], s);
        cnh[tau] = 0.5f * s;
    }

    int tile = tau >> 8;
    int rem  = tau & 255;
    int f    = rem >> 6;
    int L    = rem & 63;
    int code = tile * 16 + (L & 15);
    int kb   = (f & 1) * 32 + (L >> 4) * 8;
    int lo_f = f >> 1;
    const float* src = (code < KHALF) ? (e0 + (size_t)code * DFEAT)
                                      : (sel + (size_t)(code - KHALF) * DFEAT);
    unsigned short* dst = fragbuf + (size_t)tau * 8;
#pragma unroll
    for (int j = 0; j < 8; ++j) {
        float v = src[kb + j];
        unsigned short hb = f2bf(v);
        dst[j] = lo_f ? f2bf(v - bf2f(hb)) : hb;
    }
}

// ---------------------------------------------------------------------------
// Kernel 1: main VQ. Block = 256 threads = 4 waves; 64 rows/block
// (ONE 16-row MFMA tile per wave) -> grid 2048; B-fragments staged into
// LDS once per BLOCK (single-tile ping-pong, one barrier per tile).
// launch_bounds(256,6): VGPR cap ~42 -> no scratch spill (r11 lesson);
// 6 blocks/CU resident.
// Inner loop: verified schedule — ONE 8-deep MFMA chain per tile,
// accumulator seeded with -0.5||c||^2. Ascending-k order everywhere
// (first-min tie semantics).
// ---------------------------------------------------------------------------
#define MFMA_TILE(B0, B1, B2, B3, CN, KT)                                      \
    {                                                                          \
        const int kt_ = (KT);                                                  \
        f32x4 acc = {CN, CN, CN, CN};                                          \
        acc = __builtin_amdgcn_mfma_f32_16x16x32_bf16(ahi0, B0, acc, 0, 0, 0); \
        acc = __builtin_amdgcn_mfma_f32_16x16x32_bf16(ahi1, B1, acc, 0, 0, 0); \
        acc = __builtin_amdgcn_mfma_f32_16x16x32_bf16(ahi0, B2, acc, 0, 0, 0); \
        acc = __builtin_amdgcn_mfma_f32_16x16x32_bf16(ahi1, B3, acc, 0, 0, 0); \
        acc = __builtin_amdgcn_mfma_f32_16x16x32_bf16(alo0, B0, acc, 0, 0, 0); \
        acc = __builtin_amdgcn_mfma_f32_16x16x32_bf16(alo1, B1, acc, 0, 0, 0); \
        acc = __builtin_amdgcn_mfma_f32_16x16x32_bf16(alo0, B2, acc, 0, 0, 0); \
        acc = __builtin_amdgcn_mfma_f32_16x16x32_bf16(alo1, B3, acc, 0, 0, 0); \
        _Pragma("unroll")                                                      \
        for (int r = 0; r < 4; ++r) {                                          \
            if (acc[r] > best[r]) { best[r] = acc[r]; bidx[r] = kt_; }         \
        }                                                                      \
    }

__global__ __launch_bounds__(256, 6) void vq_main(
        const float* __restrict__ x,
        const float* __restrict__ e0, const float* __restrict__ e1,
        const float* __restrict__ e2, const int* __restrict__ idxp,
        const float* __restrict__ cnh, const unsigned short* __restrict__ fragbuf,
        float* __restrict__ out, float* __restrict__ loss_acc,
        int* __restrict__ hist) {
    __shared__ float  xsq_s[64];
    __shared__ float  sc_s[64];
    __shared__ int    bk_s[64];
    __shared__ bf16x8 ldsf[2][4][64];   // ping-pong tile fragments, 8 KB

    const int t = threadIdx.x;
    const int w = t >> 6;          // wave in block (owns rows [w*16, w*16+16))
    const int L = t & 63;          // lane
    const int q = L >> 4;          // quad
    const int m = L & 15;

    const int rowbase = blockIdx.x * 64;   // 2048 blocks; never straddles an image
    const int n  = rowbase >> 12;
    const int s0 = rowbase & 4095;

    const int idx = idxp[0];
    const float* sel = (idx == 2) ? e2 : e1;
    const int ntiles = (idx == 0) ? 32 : 64;   // always even

    // ---- A fragments: one 16-row tile per wave, hi/lo bf16 + ||x||^2 ----
    bf16x8 ahi0, ahi1, alo0, alo1;
    {
        const float* xr = x + (size_t)n * CHW + (s0 + w * 16) + m;
        float xs = 0.f;
#pragma unroll
        for (int h = 0; h < 2; ++h) {
            bf16x8 hi, lo;
#pragma unroll
            for (int j = 0; j < 8; ++j) {
                int c = h * 32 + q * 8 + j;
                float v = xr[(size_t)c * HW];
                xs = fmaf(v, v, xs);
                unsigned short hb = f2bf(v);
                unsigned short lb = f2bf(v - bf2f(hb));
                hi[j] = (short)hb;
                lo[j] = (short)lb;
            }
            if (h == 0) { ahi0 = hi; alo0 = lo; } else { ahi1 = hi; alo1 = lo; }
        }
        // full ||x_row||^2: row features live in lanes {m, m+16, m+32, m+48}
        xs += __shfl_xor(xs, 16, 64);
        xs += __shfl_xor(xs, 32, 64);
        if (q == 0) xsq_s[w * 16 + m] = xs;
    }

    // ---- stream code tiles via LDS; score = x.c - 0.5||c||^2, argMAX ----
    const bf16x8* fb = (const bf16x8*)fragbuf;
    float best[4];
    int   bidx[4];
#pragma unroll
    for (int i = 0; i < 4; ++i) { best[i] = -3.4e38f; bidx[i] = 0; }

    // prologue: stage tile 0 into buf0; start tile 1's fragment in flight
    bf16x8 P = fb[(0 * 4 + w) * 64 + L];
    ldsf[0][w][L] = P;                               // waits on P, ds_write
    P = fb[(1 * 4 + w) * 64 + L];                    // tile 1 frag in flight
    __syncthreads();                                 // buf0 ready
    float Xc = -cnh[m];                              // tile 0 cn
    float Yc;
    bf16x8 Q;

    for (int tt = 0; tt < ntiles; tt += 2) {
        // ---- STEP A: compute tile tt from buf0; stage tile tt+1 -> buf1 ----
        {
            const int tq = (tt + 2 < ntiles) ? tt + 2 : ntiles - 1;
            Q  = fb[(tq * 4 + w) * 64 + L];          // prefetch tile tt+2 frag
            Yc = -cnh[(tt + 1) * 16 + m];
            bf16x8 b0 = ldsf[0][0][L];
            bf16x8 b1 = ldsf[0][1][L];
            bf16x8 b2 = ldsf[0][2][L];
            bf16x8 b3 = ldsf[0][3][L];
            MFMA_TILE(b0, b1, b2, b3, Xc, tt * 16 + m);
            ldsf[1][w][L] = P;                       // tile tt+1 into buf1
            __syncthreads();
        }
        // ---- STEP B: compute tile tt+1 from buf1; stage tile tt+2 -> buf0 ----
        {
            const int tp = (tt + 3 < ntiles) ? tt + 3 : ntiles - 1;
            P  = fb[(tp * 4 + w) * 64 + L];          // prefetch tile tt+3 frag
            Xc = -cnh[((tt + 2 < ntiles) ? tt + 2 : ntiles - 1) * 16 + m];
            bf16x8 b0 = ldsf[1][0][L];
            bf16x8 b1 = ldsf[1][1][L];
            bf16x8 b2 = ldsf[1][2][L];
            bf16x8 b3 = ldsf[1][3][L];
            MFMA_TILE(b0, b1, b2, b3, Yc, (tt + 1) * 16 + m);
            ldsf[0][w][L] = Q;                       // tile tt+2 into buf0
            __syncthreads();
        }
    }

    // ---- reduce argmax across the 16 cols (lane bits 0-3) ----
#pragma unroll
    for (int i = 0; i < 4; ++i) {
        float b = best[i]; int k = bidx[i];
#pragma unroll
        for (int off = 1; off < 16; off <<= 1) {
            float ob = __shfl_xor(b, off, 64);
            int   ok = __shfl_xor(k, off, 64);
            if (ob > b || (ob == b && ok < k)) { b = ob; k = ok; }
        }
        if (m == 0) {   // D row = q*4 + i
            int row = w * 16 + q * 4 + i;
            sc_s[row] = b; bk_s[row] = k;
        }
    }
    __syncthreads();

    // ---- epilogue part 1: loss + histogram, one thread per row (t < 64) ----
    if (t < 64) {
        const int k = bk_s[t];
        float dist = xsq_s[t] - 2.f * sc_s[t];   // ||x||^2 - 2x.c + ||c||^2
        float l = dist;
#pragma unroll
        for (int off = 32; off > 0; off >>= 1) l += __shfl_down(l, off, 64);
        if (L == 0) atomicAdd(loss_acc, l);
        atomicAdd(&hist[k], 1);
    }

    // ---- epilogue part 2: gather-copy, 4 threads per row (16 feats each) ----
    {
        const int row  = t & 63;
        const int quad = t >> 6;
        const int k = bk_s[row];
        const float* cp = ((k < KHALF) ? (e0 + (size_t)k * DFEAT)
                                       : (sel + (size_t)(k - KHALF) * DFEAT)) + quad * 16;
        const float4* cp4 = (const float4*)cp;
        float* op = out + (size_t)n * CHW + (s0 + row);
#pragma unroll
        for (int c4 = 0; c4 < 4; ++c4) {
            float4 v = cp4[c4];
            int c = quad * 16 + 4 * c4;
            op[(size_t)(c + 0) * HW] = v.x;
            op[(size_t)(c + 1) * HW] = v.y;
            op[(size_t)(c + 2) * HW] = v.z;
            op[(size_t)(c + 3) * HW] = v.w;
        }
    }
}

// ---------------------------------------------------------------------------
// Kernel 2: finalize — loss scalar + perplexity from histogram. One block.
// Cross-kernel visibility of hist/loss comes from the dispatch boundary.
// ---------------------------------------------------------------------------
__global__ void vq_finalize(const float* __restrict__ wsf, const int* __restrict__ hist,
                            float* __restrict__ out) {
    __shared__ double partial[16];
    const int t = threadIdx.x;          // 1024 threads, one per bin
    double p = (double)hist[t] / (double)NROWS;
    double term = p * log(p + 1e-10);   // p==0 -> exactly 0
#pragma unroll
    for (int off = 32; off > 0; off >>= 1) term += __shfl_down(term, off, 64);
    if ((t & 63) == 0) partial[t >> 6] = term;
    __syncthreads();
    if (t == 0) {
        double s = 0.0;
        for (int i = 0; i < 16; ++i) s += partial[i];
        out[NQOUT + 1] = (float)exp(-s);                       // perplexity
        out[NQOUT]     = 1.25f * (wsf[0] / (float)NQOUT);      // q_loss + 0.25*e_loss
    }
}

// ---------------------------------------------------------------------------
extern "C" void kernel_launch(void* const* d_in, const int* in_sizes, int n_in,
                              void* d_out, int out_size, void* d_ws, size_t ws_size,
                              hipStream_t stream) {
    const float* x  = (const float*)d_in[0];
    const float* e0 = (const float*)d_in[1];
    const float* e1 = (const float*)d_in[2];
    const float* e2 = (const float*)d_in[3];
    const int* idxp = (const int*)d_in[4];
    float* out = (float*)d_out;

    // ws layout (floats): [0] loss | [256..1280) hist
    //                     [2048..3072) cnh | [4096..) fragbuf: 131072 ushort
    float* wsf      = (float*)d_ws;
    float* loss_acc = wsf;
    int*   hist     = (int*)(wsf + 256);
    float* cnh      = wsf + 2048;
    unsigned short* fragbuf = (unsigned short*)(wsf + 4096);

    vq_prep<<<64, 256, 0, stream>>>(e0, e1, e2, idxp, wsf, cnh, fragbuf);
    vq_main<<<NBLK, 256, 0, stream>>>(x, e0, e1, e2, idxp, cnh, fragbuf,
                                      out, loss_acc, hist);
    vq_finalize<<<1, 1024, 0, stream>>>(wsf, hist, out);
}